// Round 16
// baseline (420.923 us; speedup 1.0000x reference)
//
#include <hip/hip_runtime.h>

#define INF_F __builtin_inff()

typedef unsigned short u16;
typedef __attribute__((ext_vector_type(8))) short s16x8;   // 8 bf16 (4 VGPRs)
typedef __attribute__((ext_vector_type(4))) float f32x4;   // MFMA accum

union U8 { uint4 q; s16x8 v; };

__device__ __forceinline__ float b2f(u16 u) {
    union { unsigned int i; float f; } v; v.i = ((unsigned int)u) << 16; return v.f;
}
__device__ __forceinline__ u16 f2b(float f) {
    union { float f; unsigned int i; } v; v.f = f;
    unsigned int r = (v.i + 0x7FFFu + ((v.i >> 16) & 1u)) >> 16;
    return (u16)r;
}
__device__ __forceinline__ void bf2x(unsigned int p, float& lo, float& hi) {
    union { unsigned int i; float f; } a, b;
    a.i = p << 16; b.i = p & 0xFFFF0000u;
    lo = a.f; hi = b.f;
}
__device__ __forceinline__ unsigned int packbf(float lo, float hi) {
    return (unsigned int)f2b(lo) | ((unsigned int)f2b(hi) << 16);
}

// ---------------------------------------------------------------------------
// k_prep: pack all 4 weights into bf16 MFMA-B layout + edge degree count.
// ---------------------------------------------------------------------------
__device__ __forceinline__ void pack_one(const float* __restrict__ W, int K, int N,
                                         int Npad, u16* __restrict__ pb, int idx)
{
    int k = idx / Npad, n = idx - k * Npad;
    float v = (n < N) ? W[(size_t)k * N + n] : 0.f;
    int K5 = K >> 5;
    size_t o = ((size_t)(n >> 4) * K5 + (k >> 5)) * 512
             + ((size_t)((k >> 3) & 3)) * 128 + (n & 15) * 8 + (k & 7);
    pb[o] = f2b(v);
}

__launch_bounds__(256)
__global__ void k_prep(const float* __restrict__ fw_W, const float* __restrict__ c1_W,
                       const float* __restrict__ c2_W, const float* __restrict__ l2_W,
                       u16* __restrict__ pb_l1, u16* __restrict__ pb_c1,
                       u16* __restrict__ pb_c2, u16* __restrict__ pb_f,
                       const int* __restrict__ dst, int E, int* __restrict__ counts)
{
    int idx = blockIdx.x * 256 + threadIdx.x;
    if (idx < 32768) { pack_one(fw_W, 256, 128, 128, pb_l1, idx); return; }
    idx -= 32768;
    if (idx < 65536) { pack_one(c1_W, 128, 512, 512, pb_c1, idx); return; }
    idx -= 65536;
    if (idx < 65536) { pack_one(c2_W, 512, 128, 128, pb_c2, idx); return; }
    idx -= 65536;
    if (idx < 49152) { pack_one(l2_W, 768, 40, 64, pb_f, idx); return; }
    idx -= 49152;
    if (idx < E) atomicAdd(&counts[dst[idx]], 1);
}

// ---------------------------------------------------------------------------
// Device parts (called from fused union kernels; bid = local block index).
// ---------------------------------------------------------------------------
__device__ void dev_l1gemm(const float* __restrict__ x, const u16* __restrict__ pb,
                           u16* __restrict__ h1, int M, const float* __restrict__ bias,
                           int bid)
{
    const int tid = threadIdx.x;
    const int w = tid >> 6, l = tid & 63;
    const int lo = l & 15, hi = l >> 4;
    const int row0 = bid * 128 + w * 32;
    if (row0 >= M) return;

    f32x4 acc[8][2];
    #pragma unroll
    for (int i = 0; i < 8; ++i)
        #pragma unroll
        for (int s = 0; s < 2; ++s) acc[i][s] = (f32x4){0.f, 0.f, 0.f, 0.f};

    int arow[2];
    #pragma unroll
    for (int s = 0; s < 2; ++s) {
        int r = row0 + s * 16 + lo;
        arow[s] = r < M ? r : M - 1;
    }

    for (int k5 = 0; k5 < 8; ++k5) {
        const int ak = k5 * 32 + hi * 8;
        s16x8 af[2];
        #pragma unroll
        for (int s = 0; s < 2; ++s) {
            const float* A = x + (size_t)arow[s] * 256 + ak;
            float4 v0 = *reinterpret_cast<const float4*>(A);
            float4 v1 = *reinterpret_cast<const float4*>(A + 4);
            U8 au;
            au.q.x = packbf(v0.x, v0.y); au.q.y = packbf(v0.z, v0.w);
            au.q.z = packbf(v1.x, v1.y); au.q.w = packbf(v1.z, v1.w);
            af[s] = au.v;
        }
        #pragma unroll
        for (int cb = 0; cb < 8; ++cb) {
            s16x8 bf = *reinterpret_cast<const s16x8*>(pb + ((size_t)cb * 8 + k5) * 512 + l * 8);
            acc[cb][0] = __builtin_amdgcn_mfma_f32_16x16x32_bf16(af[0], bf, acc[cb][0], 0, 0, 0);
            acc[cb][1] = __builtin_amdgcn_mfma_f32_16x16x32_bf16(af[1], bf, acc[cb][1], 0, 0, 0);
        }
    }

    #pragma unroll
    for (int cb = 0; cb < 8; ++cb) {
        int col = cb * 16 + lo;
        #pragma unroll
        for (int s = 0; s < 2; ++s) {
            #pragma unroll
            for (int p = 0; p < 4; ++p) {
                int r = row0 + s * 16 + hi * 4 + p;
                if (r < M) {
                    float v = acc[cb][s][p] + bias[col];
                    v = v >= 0.f ? v : 0.01f * v;
                    h1[(size_t)r * 128 + col] = f2b(v);
                }
            }
        }
    }
}

__device__ void dev_scan1(const int* __restrict__ counts, int n,
                          int* __restrict__ rowstart, int* __restrict__ tilesum,
                          int* __restrict__ fill, int bid)
{
    const int tid = threadIdx.x;
    const int lane = tid & 63, w = tid >> 6;
    const int i0 = bid * 1024 + tid * 4;
    int v0 = 0, v1 = 0, v2 = 0, v3 = 0;
    if (i0 + 3 < n) {
        int4 q = *reinterpret_cast<const int4*>(counts + i0);
        v0 = q.x; v1 = q.y; v2 = q.z; v3 = q.w;
    } else if (i0 < n) {
        v0 = counts[i0];
        if (i0 + 1 < n) v1 = counts[i0 + 1];
        if (i0 + 2 < n) v2 = counts[i0 + 2];
    }
    if (i0 < n) {
        int4 z = make_int4(0, 0, 0, 0);
        if (i0 + 3 < n) *reinterpret_cast<int4*>(fill + i0) = z;
        else {
            fill[i0] = 0;
            if (i0 + 1 < n) fill[i0 + 1] = 0;
            if (i0 + 2 < n) fill[i0 + 2] = 0;
        }
    }
    int s1 = v0 + v1, s2 = s1 + v2, s3 = s2 + v3;
    int x = s3;
    #pragma unroll
    for (int off = 1; off < 64; off <<= 1) {
        int t = __shfl_up(x, off, 64);
        if (lane >= off) x += t;
    }
    __shared__ int wsum[4];
    if (lane == 63) wsum[w] = x;
    __syncthreads();
    int woff = 0;
    #pragma unroll
    for (int i = 0; i < 4; ++i)
        if (i < w) woff += wsum[i];
    int excl = woff + x - s3;
    if (i0 + 0 < n) rowstart[i0 + 1] = excl + v0;
    if (i0 + 1 < n) rowstart[i0 + 2] = excl + s1;
    if (i0 + 2 < n) rowstart[i0 + 3] = excl + s2;
    if (i0 + 3 < n) rowstart[i0 + 4] = excl + s3;
    if (tid == 255) tilesum[bid] = wsum[0] + wsum[1] + wsum[2] + wsum[3];
}

__device__ void dev_scan3(int* __restrict__ rowstart, const int* __restrict__ tilesum,
                          int n, int bid)
{
    const int tile = (bid * 256) >> 10;
    __shared__ int s_off;
    if (threadIdx.x < 64) {
        int lane = threadIdx.x;
        int v = (lane < tile) ? tilesum[lane] : 0;   // tile count <= 49 < 64
        #pragma unroll
        for (int m = 1; m < 64; m <<= 1) v += __shfl_xor(v, m, 64);
        if (lane == 0) s_off = v;
    }
    __syncthreads();
    int i = bid * 256 + threadIdx.x;
    if (i < n) rowstart[i + 1] += s_off;
    if (bid == 0 && threadIdx.x == 0) rowstart[0] = 0;
}

__device__ void dev_colstats(const u16* __restrict__ X, int M, int C,
                             float* __restrict__ psum, float* __restrict__ psq,
                             int bid, int nb)
{
    const int CG  = C >> 3;
    const int RPI = 256 / CG;
    const int tid = threadIdx.x;
    const int cg  = tid & (CG - 1);
    const int ro  = tid / CG;
    const int rows_chunk = (M + nb - 1) / nb;
    const int r0 = bid * rows_chunk;
    const int r1 = min(M, r0 + rows_chunk);

    float s[8] = {}, q[8] = {};
    for (int r = r0 + ro; r < r1; r += RPI) {
        uint4 u = *reinterpret_cast<const uint4*>(X + (size_t)r * C + cg * 8);
        float x[8];
        bf2x(u.x, x[0], x[1]); bf2x(u.y, x[2], x[3]);
        bf2x(u.z, x[4], x[5]); bf2x(u.w, x[6], x[7]);
        #pragma unroll
        for (int j = 0; j < 8; ++j) { s[j] += x[j]; q[j] = fmaf(x[j], x[j], q[j]); }
    }

    __shared__ float lsum[8][256];
    __shared__ float lsq [8][256];
    #pragma unroll
    for (int j = 0; j < 8; ++j) { lsum[j][tid] = s[j]; lsq[j][tid] = q[j]; }
    __syncthreads();

    if (tid < CG) {
        #pragma unroll
        for (int j = 0; j < 8; ++j) {
            float ss = 0.f, qq = 0.f;
            for (int o = 0; o < RPI; ++o) {
                ss += lsum[j][o * CG + tid];
                qq += lsq [j][o * CG + tid];
            }
            psum[(size_t)bid * C + tid * 8 + j] = ss;
            psq [(size_t)bid * C + tid * 8 + j] = qq;
        }
    }
}

__device__ void dev_colred(const float* __restrict__ psum, const float* __restrict__ psq,
                           const float* __restrict__ g, const float* __restrict__ b,
                           int nb, int M, int C,
                           float* __restrict__ scale, float* __restrict__ shift, int bid)
{
    int c = bid * 4 + ((int)threadIdx.x >> 6);
    int lane = threadIdx.x & 63;
    if (c >= C) return;
    float s = 0.f, q = 0.f;
    for (int l = lane; l < nb; l += 64) {
        s += psum[(size_t)l * C + c];
        q += psq [(size_t)l * C + c];
    }
    #pragma unroll
    for (int off = 32; off; off >>= 1) {
        s += __shfl_xor(s, off, 64);
        q += __shfl_xor(q, off, 64);
    }
    if (lane == 0) {
        float mu  = s / (float)M;
        float var = q / (float)M - mu * mu;
        float sc  = g[c] * rsqrtf(var + 1e-5f);
        scale[c] = sc;
        shift[c] = b[c] - mu * sc;
    }
}

__device__ void dev_scatter4(const int* __restrict__ ei, int E,
                             const int* __restrict__ rowstart,
                             int* __restrict__ fill, int* __restrict__ csr, int bid)
{
    int e0 = (bid * 256 + (int)threadIdx.x) * 4;
    if (e0 >= E) return;
    if (e0 + 3 < E) {
        int4 s4 = *reinterpret_cast<const int4*>(ei + e0);
        int4 d4 = *reinterpret_cast<const int4*>(ei + E + e0);
        int p0 = rowstart[d4.x] + atomicAdd(&fill[d4.x], 1); csr[p0] = s4.x;
        int p1 = rowstart[d4.y] + atomicAdd(&fill[d4.y], 1); csr[p1] = s4.y;
        int p2 = rowstart[d4.z] + atomicAdd(&fill[d4.z], 1); csr[p2] = s4.z;
        int p3 = rowstart[d4.w] + atomicAdd(&fill[d4.w], 1); csr[p3] = s4.w;
    } else {
        for (int e = e0; e < E; ++e) {
            int s = ei[e], d = ei[E + e];
            int pos = rowstart[d] + atomicAdd(&fill[d], 1);
            csr[pos] = s;
        }
    }
}

// ---------------------------------------------------------------------------
// Fused union kernels (independent work only; branch uniform per block).
// ---------------------------------------------------------------------------
__launch_bounds__(256)
__global__ void kA(const float* __restrict__ x, const u16* __restrict__ pb_l1,
                   u16* __restrict__ h1, int M, const float* __restrict__ fw_b, int mb2,
                   const int* __restrict__ counts, int n,
                   int* __restrict__ rowstart, int* __restrict__ tilesum,
                   int* __restrict__ fill)
{
    if ((int)blockIdx.x < mb2) dev_l1gemm(x, pb_l1, h1, M, fw_b, blockIdx.x);
    else                       dev_scan1(counts, n, rowstart, tilesum, fill, blockIdx.x - mb2);
}

__launch_bounds__(256)
__global__ void kB(int* __restrict__ rowstart, const int* __restrict__ tilesum, int n,
                   int nscan3, const u16* __restrict__ h1, int M,
                   float* __restrict__ psum, float* __restrict__ psq, int nb)
{
    if ((int)blockIdx.x < nscan3) dev_scan3(rowstart, tilesum, n, blockIdx.x);
    else                          dev_colstats(h1, M, 128, psum, psq, blockIdx.x - nscan3, nb);
}

__launch_bounds__(256)
__global__ void kC(const int* __restrict__ ei, int E, const int* __restrict__ rowstart,
                   int* __restrict__ fill, int* __restrict__ csr, int nscat,
                   const float* __restrict__ psum, const float* __restrict__ psq,
                   const float* __restrict__ g, const float* __restrict__ b,
                   int nb, int M, float* __restrict__ scale, float* __restrict__ shift)
{
    if ((int)blockIdx.x < nscat) dev_scatter4(ei, E, rowstart, fill, csr, blockIdx.x);
    else dev_colred(psum, psq, g, b, nb, M, 128, scale, shift, blockIdx.x - nscat);
}

// ---------------------------------------------------------------------------
// Standalone colstats/colred (BN2, BN3).
// ---------------------------------------------------------------------------
__launch_bounds__(256)
__global__ void k_colstats(const u16* __restrict__ X, int M, int C,
                           float* __restrict__ psum, float* __restrict__ psq)
{
    dev_colstats(X, M, C, psum, psq, blockIdx.x, gridDim.x);
}

__launch_bounds__(256)
__global__ void k_colred(const float* __restrict__ psum, const float* __restrict__ psq,
                         const float* __restrict__ g, const float* __restrict__ b,
                         int nb, int M, int C,
                         float* __restrict__ scale, float* __restrict__ shift)
{
    dev_colred(psum, psq, g, b, nb, M, C, scale, shift, blockIdx.x);
}

// ---------------------------------------------------------------------------
// MFMA GEMM, 2 row-fragments per wave (c1/c2 projections), BN-folded A.
// HEADS_PB>0: fused GAT alpha epilogue (NFRAG=8 -> one head per block).
// ---------------------------------------------------------------------------
template<int NFRAG, bool BN_A, int HEADS_PB>
__launch_bounds__(256)
__global__ void k_mgemm(const u16* __restrict__ Av, int lda, int K,
                        const u16* __restrict__ pb,
                        u16* __restrict__ C, int ldc, int M,
                        const float* __restrict__ scale, const float* __restrict__ shift,
                        const float* __restrict__ aw_s, const float* __restrict__ aw_d,
                        float* __restrict__ as_o, float* __restrict__ ad_o, int nheads)
{
    const int tid = threadIdx.x;
    const int w = tid >> 6, l = tid & 63;
    const int lo = l & 15, hi = l >> 4;
    const int row0 = blockIdx.y * 128 + w * 32;
    if (row0 >= M) return;
    const int cb0 = blockIdx.x * NFRAG;
    const int K5 = K >> 5;

    f32x4 acc[NFRAG][2];
    #pragma unroll
    for (int i = 0; i < NFRAG; ++i)
        #pragma unroll
        for (int s = 0; s < 2; ++s) acc[i][s] = (f32x4){0.f, 0.f, 0.f, 0.f};

    int arow[2];
    #pragma unroll
    for (int s = 0; s < 2; ++s) {
        int r = row0 + s * 16 + lo;
        arow[s] = r < M ? r : M - 1;
    }

    for (int k5 = 0; k5 < K5; ++k5) {
        const int ak = k5 * 32 + hi * 8;
        s16x8 af[2];
        #pragma unroll
        for (int s = 0; s < 2; ++s) {
            uint4 q = *reinterpret_cast<const uint4*>(Av + (size_t)arow[s] * lda + ak);
            float x[8];
            bf2x(q.x, x[0], x[1]); bf2x(q.y, x[2], x[3]);
            bf2x(q.z, x[4], x[5]); bf2x(q.w, x[6], x[7]);
            if (BN_A) {
                #pragma unroll
                for (int j = 0; j < 8; ++j) x[j] = fmaf(x[j], scale[ak + j], shift[ak + j]);
            }
            U8 au;
            au.q.x = packbf(x[0], x[1]); au.q.y = packbf(x[2], x[3]);
            au.q.z = packbf(x[4], x[5]); au.q.w = packbf(x[6], x[7]);
            af[s] = au.v;
        }
        #pragma unroll
        for (int cb = 0; cb < NFRAG; ++cb) {
            s16x8 bf = *reinterpret_cast<const s16x8*>(
                pb + ((size_t)(cb0 + cb) * K5 + k5) * 512 + l * 8);
            acc[cb][0] = __builtin_amdgcn_mfma_f32_16x16x32_bf16(af[0], bf, acc[cb][0], 0, 0, 0);
            acc[cb][1] = __builtin_amdgcn_mfma_f32_16x16x32_bf16(af[1], bf, acc[cb][1], 0, 0, 0);
        }
    }

    #pragma unroll
    for (int cb = 0; cb < NFRAG; ++cb) {
        int col = (cb0 + cb) * 16 + lo;
        #pragma unroll
        for (int s = 0; s < 2; ++s) {
            #pragma unroll
            for (int p = 0; p < 4; ++p) {
                int r = row0 + s * 16 + hi * 4 + p;
                if (r < M) C[(size_t)r * ldc + col] = f2b(acc[cb][s][p]);
            }
        }
    }

    if (HEADS_PB > 0) {
        const int h = (cb0 >> 3);
        #pragma unroll
        for (int s = 0; s < 2; ++s) {
            float ps[4] = {0.f,0.f,0.f,0.f}, pd[4] = {0.f,0.f,0.f,0.f};
            #pragma unroll
            for (int cb = 0; cb < NFRAG; ++cb) {
                int col = (cb0 + cb) * 16 + lo;
                float ws = aw_s[col], wd = aw_d[col];
                #pragma unroll
                for (int p = 0; p < 4; ++p) {
                    ps[p] = fmaf(acc[cb][s][p], ws, ps[p]);
                    pd[p] = fmaf(acc[cb][s][p], wd, pd[p]);
                }
            }
            #pragma unroll
            for (int m = 1; m < 16; m <<= 1) {
                #pragma unroll
                for (int p = 0; p < 4; ++p) {
                    ps[p] += __shfl_xor(ps[p], m, 64);
                    pd[p] += __shfl_xor(pd[p], m, 64);
                }
            }
            if (lo == 0) {
                #pragma unroll
                for (int p = 0; p < 4; ++p) {
                    int r = row0 + s * 16 + hi * 4 + p;
                    if (r < M) {
                        as_o[(size_t)r * nheads + h] = ps[p];
                        ad_o[(size_t)r * nheads + h] = pd[p];
                    }
                }
            }
        }
    }
}

// ---------------------------------------------------------------------------
// Final MFMA GEMM (K=768 concat, BN-folded, 2 row-frags/wave) + bias +
// log_softmax. out fp32 [M,40].
// ---------------------------------------------------------------------------
__launch_bounds__(256)
__global__ void k_mfinal(const u16* __restrict__ h1, const u16* __restrict__ h2,
                         const u16* __restrict__ h3,
                         const float* __restrict__ scale, const float* __restrict__ shift,
                         const u16* __restrict__ pb, const float* __restrict__ bias,
                         float* __restrict__ out, int M)
{
    const int tid = threadIdx.x;
    const int w = tid >> 6, l = tid & 63;
    const int lo = l & 15, hi = l >> 4;
    const int row0 = blockIdx.x * 128 + w * 32;
    if (row0 >= M) return;
    const int K5 = 24;

    f32x4 acc[4][2];
    #pragma unroll
    for (int i = 0; i < 4; ++i)
        #pragma unroll
        for (int s = 0; s < 2; ++s) acc[i][s] = (f32x4){0.f, 0.f, 0.f, 0.f};

    int arow[2];
    #pragma unroll
    for (int s = 0; s < 2; ++s) {
        int r = row0 + s * 16 + lo;
        arow[s] = r < M ? r : M - 1;
    }

    for (int k5 = 0; k5 < K5; ++k5) {
        const int kk = k5 * 32 + hi * 8;
        const u16* src; int ld, offk;
        if (kk < 128)      { src = h1; ld = 128; offk = kk; }
        else if (kk < 640) { src = h2; ld = 512; offk = kk - 128; }
        else               { src = h3; ld = 128; offk = kk - 640; }
        s16x8 af[2];
        #pragma unroll
        for (int s = 0; s < 2; ++s) {
            uint4 q = *reinterpret_cast<const uint4*>(src + (size_t)arow[s] * ld + offk);
            float x[8];
            bf2x(q.x, x[0], x[1]); bf2x(q.y, x[2], x[3]);
            bf2x(q.z, x[4], x[5]); bf2x(q.w, x[6], x[7]);
            #pragma unroll
            for (int j = 0; j < 8; ++j) x[j] = fmaf(x[j], scale[kk + j], shift[kk + j]);
            U8 au;
            au.q.x = packbf(x[0], x[1]); au.q.y = packbf(x[2], x[3]);
            au.q.z = packbf(x[4], x[5]); au.q.w = packbf(x[6], x[7]);
            af[s] = au.v;
        }
        #pragma unroll
        for (int cb = 0; cb < 4; ++cb) {
            s16x8 bf = *reinterpret_cast<const s16x8*>(pb + ((size_t)cb * K5 + k5) * 512 + l * 8);
            acc[cb][0] = __builtin_amdgcn_mfma_f32_16x16x32_bf16(af[0], bf, acc[cb][0], 0, 0, 0);
            acc[cb][1] = __builtin_amdgcn_mfma_f32_16x16x32_bf16(af[1], bf, acc[cb][1], 0, 0, 0);
        }
    }

    #pragma unroll
    for (int s = 0; s < 2; ++s) {
        #pragma unroll
        for (int p = 0; p < 4; ++p) {
            int r = row0 + s * 16 + hi * 4 + p;
            float z0 = acc[0][s][p] + bias[lo];
            float z1 = acc[1][s][p] + bias[16 + lo];
            float z2 = -INF_F;
            if (lo < 8) z2 = acc[2][s][p] + bias[32 + lo];
            float mx = fmaxf(fmaxf(z0, z1), z2);
            #pragma unroll
            for (int m = 1; m < 16; m <<= 1) mx = fmaxf(mx, __shfl_xor(mx, m, 64));
            float se = __expf(z0 - mx) + __expf(z1 - mx) + ((lo < 8) ? __expf(z2 - mx) : 0.f);
            #pragma unroll
            for (int m = 1; m < 16; m <<= 1) se += __shfl_xor(se, m, 64);
            float lse = mx + __logf(se);
            if (r < M) {
                out[(size_t)r * 40 + lo]      = z0 - lse;
                out[(size_t)r * 40 + 16 + lo] = z1 - lse;
                if (lo < 8) out[(size_t)r * 40 + 32 + lo] = z2 - lse;
            }
        }
    }
}

// ---------------------------------------------------------------------------
// GAT aggregation, HEADS=4: one wave per dst, two-pass softmax,
// depth-8 prefetch / unroll-4. lane l: head=l>>4, dims (l&15)*8..+8.
// ---------------------------------------------------------------------------
__launch_bounds__(256)
__global__ void k_gat_agg_h4(const u16* __restrict__ hp,
                             const float* __restrict__ as_, const float* __restrict__ ad_,
                             const int* __restrict__ rowstart, const int* __restrict__ csr,
                             const float* __restrict__ bias, u16* __restrict__ out, int Nn)
{
    int d = (int)((blockIdx.x * (size_t)blockDim.x + threadIdx.x) >> 6);
    int lane = threadIdx.x & 63;
    if (d >= Nn) return;
    const int h = lane >> 4;
    const int li = lane & 15;
    const int dim = li * 8;
    int e0 = rowstart[d], e1 = rowstart[d + 1];
    float adv = ad_[(size_t)d * 4 + h];

    float mx = -INF_F;
    for (int j = e0 + li; j < e1; j += 16) {
        int s = csr[j];
        float e = as_[(size_t)s * 4 + h] + adv;
        e = e >= 0.f ? e : 0.2f * e;
        mx = fmaxf(mx, e);
    }
    #pragma unroll
    for (int m = 1; m < 16; m <<= 1) mx = fmaxf(mx, __shfl_xor(mx, m, 64));

    float lsum = 0.f;
    float acc[8] = {};

    #define F4(J, A, U) { int jj = min((J), e1 - 1); int s_ = csr[jj];                \
        A = as_[(size_t)s_ * 4 + h];                                                  \
        U = *reinterpret_cast<const uint4*>(hp + ((size_t)s_ * 4 + h) * 128 + dim); }
    #define C4(A, U) { float e_ = A + adv; e_ = e_ >= 0.f ? e_ : 0.2f * e_;           \
        float w_ = __expf(e_ - mx); lsum += w_;                                       \
        float x_[8];                                                                  \
        bf2x(U.x, x_[0], x_[1]); bf2x(U.y, x_[2], x_[3]);                             \
        bf2x(U.z, x_[4], x_[5]); bf2x(U.w, x_[6], x_[7]);                             \
        _Pragma("unroll")                                                             \
        for (int t_ = 0; t_ < 8; ++t_) acc[t_] = fmaf(x_[t_], w_, acc[t_]); }

    float a0, a1, a2, a3, a4, a5, a6, a7;
    uint4 u0, u1, u2, u3, u4, u5, u6, u7;
    F4(e0 + 0, a0, u0); F4(e0 + 1, a1, u1); F4(e0 + 2, a2, u2); F4(e0 + 3, a3, u3);
    F4(e0 + 4, a4, u4); F4(e0 + 5, a5, u5); F4(e0 + 6, a6, u6); F4(e0 + 7, a7, u7);

    int j = e0;
    for (; j + 3 < e1; j += 4) {
        C4(a0, u0); C4(a1, u1); C4(a2, u2); C4(a3, u3);
        a0 = a4; u0 = u4; a1 = a5; u1 = u5; a2 = a6; u2 = u6; a3 = a7; u3 = u7;
        F4(j + 8, a4, u4); F4(j + 9, a5, u5); F4(j + 10, a6, u6); F4(j + 11, a7, u7);
    }
    if (j < e1)     C4(a0, u0);
    if (j + 1 < e1) C4(a1, u1);
    if (j + 2 < e1) C4(a2, u2);
    #undef F4
    #undef C4

    float inv = 1.f / (lsum + 1e-16f);
    const int ob = h * 128 + dim;
    float v[8];
    #pragma unroll
    for (int t = 0; t < 8; ++t) {
        float z = acc[t] * inv + bias[ob + t];
        v[t] = z >= 0.f ? z : 0.01f * z;
    }
    uint4 o;
    o.x = packbf(v[0], v[1]); o.y = packbf(v[2], v[3]);
    o.z = packbf(v[4], v[5]); o.w = packbf(v[6], v[7]);
    *reinterpret_cast<uint4*>(out + (size_t)d * 512 + ob) = o;
}

// ---------------------------------------------------------------------------
// GAT aggregation, HEADS=1: two dsts per wave, split-half, two-pass softmax,
// depth-8 prefetch / unroll-4.
// ---------------------------------------------------------------------------
__launch_bounds__(256)
__global__ void k_gat_agg_h1(const u16* __restrict__ hp,
                             const float* __restrict__ as_, const float* __restrict__ ad_,
                             const int* __restrict__ rowstart, const int* __restrict__ csr,
                             const float* __restrict__ bias, u16* __restrict__ out, int Nn)
{
    const int lane = threadIdx.x & 63;
    const int half = lane >> 5;
    const int sl = lane & 31;
    const int wave = (int)((blockIdx.x * (size_t)blockDim.x + threadIdx.x) >> 6);
    const int d = wave * 2 + half;
    if (wave * 2 >= Nn) return;
    const bool act = d < Nn;
    const int dc = act ? d : (Nn - 1);
    const int dim = sl * 4;
    int e0 = rowstart[dc], e1 = rowstart[dc + 1];
    int len = e1 - e0;
    float adv = ad_[dc];

    float mx = -INF_F;
    for (int j = e0 + sl; j < e1; j += 32) {
        int s = csr[j];
        float e = as_[s] + adv;
        e = e >= 0.f ? e : 0.2f * e;
        mx = fmaxf(mx, e);
    }
    #pragma unroll
    for (int m = 1; m < 32; m <<= 1) mx = fmaxf(mx, __shfl_xor(mx, m, 32));

    int maxlen = max(len, __shfl_xor(len, 32, 64));

    float lsum = 0.f;
    float acc[4] = {};

    #define F1(JR, A, U) { int jj = e0 + min((JR), len - 1); int s_ = csr[jj];        \
        A = as_[s_];                                                                  \
        U = *reinterpret_cast<const uint2*>(hp + (size_t)s_ * 128 + dim); }
    #define C1(JR, A, U) { float e_ = A + adv; e_ = e_ >= 0.f ? e_ : 0.2f * e_;       \
        float w_ = ((JR) < len) ? __expf(e_ - mx) : 0.f;                              \
        float x0_, x1_, x2_, x3_; bf2x(U.x, x0_, x1_); bf2x(U.y, x2_, x3_);           \
        lsum += w_;                                                                   \
        acc[0] = fmaf(x0_, w_, acc[0]); acc[1] = fmaf(x1_, w_, acc[1]);               \
        acc[2] = fmaf(x2_, w_, acc[2]); acc[3] = fmaf(x3_, w_, acc[3]); }

    float a0, a1, a2, a3, a4, a5, a6, a7;
    uint2 u0, u1, u2, u3, u4, u5, u6, u7;
    F1(0, a0, u0); F1(1, a1, u1); F1(2, a2, u2); F1(3, a3, u3);
    F1(4, a4, u4); F1(5, a5, u5); F1(6, a6, u6); F1(7, a7, u7);

    int jr = 0;
    for (; jr + 3 < maxlen; jr += 4) {
        C1(jr + 0, a0, u0); C1(jr + 1, a1, u1); C1(jr + 2, a2, u2); C1(jr + 3, a3, u3);
        a0 = a4; u0 = u4; a1 = a5; u1 = u5; a2 = a6; u2 = u6; a3 = a7; u3 = u7;
        F1(jr + 8, a4, u4); F1(jr + 9, a5, u5); F1(jr + 10, a6, u6); F1(jr + 11, a7, u7);
    }
    if (jr < maxlen)     C1(jr + 0, a0, u0);
    if (jr + 1 < maxlen) C1(jr + 1, a1, u1);
    if (jr + 2 < maxlen) C1(jr + 2, a2, u2);
    #undef F1
    #undef C1

    float inv = 1.f / (lsum + 1e-16f);
    float v0 = acc[0] * inv + bias[dim];
    float v1 = acc[1] * inv + bias[dim + 1];
    float v2 = acc[2] * inv + bias[dim + 2];
    float v3 = acc[3] * inv + bias[dim + 3];
    v0 = v0 >= 0.f ? v0 : 0.01f * v0;
    v1 = v1 >= 0.f ? v1 : 0.01f * v1;
    v2 = v2 >= 0.f ? v2 : 0.01f * v2;
    v3 = v3 >= 0.f ? v3 : 0.01f * v3;
    if (act) {
        uint2 o;
        o.x = packbf(v0, v1);
        o.y = packbf(v2, v3);
        *reinterpret_cast<uint2*>(out + (size_t)d * 128 + dim) = o;
    }
}

// ---------------------------------------------------------------------------
extern "C" void kernel_launch(void* const* d_in, const int* in_sizes, int n_in,
                              void* d_out, int out_size, void* d_ws, size_t ws_size,
                              hipStream_t stream)
{
    const float* x     = (const float*)d_in[0];
    const int*   ei    = (const int*)  d_in[1];
    const float* fw_W  = (const float*)d_in[2];
    const float* fw_b  = (const float*)d_in[3];
    const float* c1_W  = (const float*)d_in[4];
    const float* c1_as = (const float*)d_in[5];
    const float* c1_ad = (const float*)d_in[6];
    const float* c1_b  = (const float*)d_in[7];
    const float* c2_W  = (const float*)d_in[8];
    const float* c2_as = (const float*)d_in[9];
    const float* c2_ad = (const float*)d_in[10];
    const float* c2_b  = (const float*)d_in[11];
    const float* bn1_g = (const float*)d_in[12];
    const float* bn1_b = (const float*)d_in[13];
    const float* bn2_g = (const float*)d_in[14];
    const float* bn2_b = (const float*)d_in[15];
    const float* bn3_g = (const float*)d_in[16];
    const float* bn3_b = (const float*)d_in[17];
    const float* l2_W  = (const float*)d_in[18];
    const float* l2_b  = (const float*)d_in[19];
    float* out = (float*)d_out;

    const int N = in_sizes[0] / 256;   // 50000
    const int E = in_sizes[1] / 2;     // 850000
    const int NB = 256;

    char* base = (char*)d_ws;
    size_t off = 0;
    auto alloc = [&](size_t bytes) -> void* {
        void* p = (void*)(base + off);
        off = (off + bytes + 255) & ~(size_t)255;
        return p;
    };
    // --- zeroed region (counts only; fill zeroed by scan1) ---
    int*   counts = (int*)  alloc((size_t)N * 4);
    size_t zero_bytes = off;
    // --- rest ---
    const int SCB = (N + 1023) / 1024;
    int*   fill     = (int*)  alloc((size_t)N * 4);
    float* as1      = (float*)alloc((size_t)N * 4 * 4);
    float* ad1      = (float*)alloc((size_t)N * 4 * 4);
    float* as2      = (float*)alloc((size_t)N * 4);
    float* ad2      = (float*)alloc((size_t)N * 4);
    float* psum     = (float*)alloc((size_t)NB * 512 * 4);
    float* psq      = (float*)alloc((size_t)NB * 512 * 4);
    int*   rowstart = (int*)  alloc((size_t)(N + 1) * 4);
    int*   tilesum  = (int*)  alloc((size_t)SCB * 4);
    int*   csr      = (int*)  alloc((size_t)E * 4);
    float* scale768 = (float*)alloc(768 * 4);
    float* shift768 = (float*)alloc(768 * 4);
    u16*   pb_l1    = (u16*)  alloc((size_t)256 * 128 * 2);
    u16*   pb_c1    = (u16*)  alloc((size_t)128 * 512 * 2);
    u16*   pb_c2    = (u16*)  alloc((size_t)512 * 128 * 2);
    u16*   pb_f     = (u16*)  alloc((size_t)768 * 64 * 2);
    u16*   h1       = (u16*)  alloc((size_t)N * 128 * 2);
    u16*   h2       = (u16*)  alloc((size_t)N * 512 * 2);
    u16*   hp1      = (u16*)  alloc((size_t)N * 512 * 2);  // dead after agg1:
    u16*   hp2      = hp1;                                  //  reuse for hp2 [N,128]
    u16*   h3       = hp1 + (size_t)N * 128;                //  and h3 [N,128]
    (void)ws_size; (void)n_in; (void)out_size;

    const int mb2 = (N + 127) / 128;                 // 391
    const int nscan3 = (N + 255) / 256;              // 196
    const int nscat4 = (E + 1023) / 1024;            // 831
    const int wave_blocks = (int)(((size_t)N * 64 + 255) / 256);
    const int h1_wave_blocks = (int)((((size_t)N + 1) / 2 * 64 + 255) / 256);
    const int PK = 32768 + 65536 + 65536 + 49152;

    hipMemsetAsync(base, 0, zero_bytes, stream);

    // pack all weights + edge count (one launch)
    k_prep<<<(PK + E + 255) / 256, 256, 0, stream>>>(
        fw_W, c1_W, c2_W, l2_W, pb_l1, pb_c1, pb_c2, pb_f, ei + E, E, counts);

    // kA: layer-1 GEMM ∪ scan1 (both depend only on prep)
    kA<<<mb2 + SCB, 256, 0, stream>>>(
        x, pb_l1, h1, N, fw_b, mb2, counts, N, rowstart, tilesum, fill);

    // kB: scan3 ∪ colstats1
    kB<<<nscan3 + NB, 256, 0, stream>>>(
        rowstart, tilesum, N, nscan3, h1, N, psum, psq, NB);

    // kC: scatter (x4 vectorized) ∪ colred1
    kC<<<nscat4 + (128 + 3) / 4, 256, 0, stream>>>(
        ei, E, rowstart, fill, csr, nscat4,
        psum, psq, bn1_g, bn1_b, NB, N, scale768, shift768);

    // conv1 projection + fused alpha (1 head per 128-col block)
    k_mgemm<8, true, 1><<<dim3(4, mb2), 256, 0, stream>>>(
        h1, 128, 128, pb_c1, hp1, 512, N, scale768, shift768,
        c1_as, c1_ad, as1, ad1, 4);
    k_gat_agg_h4<<<wave_blocks, 256, 0, stream>>>(
        hp1, as1, ad1, rowstart, csr, c1_b, h2, N);

    // BN2
    k_colstats<<<NB, 256, 0, stream>>>(h2, N, 512, psum, psq);
    k_colred<<<(512 + 3) / 4, 256, 0, stream>>>(psum, psq, bn2_g, bn2_b, NB, N, 512,
                                                scale768 + 128, shift768 + 128);

    // conv2 projection + fused alpha
    k_mgemm<8, true, 1><<<dim3(1, mb2), 256, 0, stream>>>(
        h2, 512, 512, pb_c2, hp2, 128, N, scale768 + 128, shift768 + 128,
        c2_as, c2_ad, as2, ad2, 1);
    k_gat_agg_h1<<<h1_wave_blocks, 256, 0, stream>>>(
        hp2, as2, ad2, rowstart, csr, c2_b, h3, N);

    // BN3
    k_colstats<<<NB, 256, 0, stream>>>(h3, N, 128, psum, psq);
    k_colred<<<(128 + 3) / 4, 256, 0, stream>>>(psum, psq, bn3_g, bn3_b, NB, N, 128,
                                                scale768 + 640, shift768 + 640);

    // final fused GEMM + log_softmax
    k_mfinal<<<mb2, 256, 0, stream>>>(h1, h2, h3, scale768, shift768, pb_f, l2_b, out, N);
}

// Round 17
// 411.833 us; speedup vs baseline: 1.0221x; 1.0221x over previous
//
#include <hip/hip_runtime.h>

#define INF_F __builtin_inff()

typedef unsigned short u16;
typedef __attribute__((ext_vector_type(8))) short s16x8;   // 8 bf16 (4 VGPRs)
typedef __attribute__((ext_vector_type(4))) float f32x4;   // MFMA accum

union U8 { uint4 q; s16x8 v; };

__device__ __forceinline__ float b2f(u16 u) {
    union { unsigned int i; float f; } v; v.i = ((unsigned int)u) << 16; return v.f;
}
__device__ __forceinline__ u16 f2b(float f) {
    union { float f; unsigned int i; } v; v.f = f;
    unsigned int r = (v.i + 0x7FFFu + ((v.i >> 16) & 1u)) >> 16;
    return (u16)r;
}
__device__ __forceinline__ void bf2x(unsigned int p, float& lo, float& hi) {
    union { unsigned int i; float f; } a, b;
    a.i = p << 16; b.i = p & 0xFFFF0000u;
    lo = a.f; hi = b.f;
}
__device__ __forceinline__ unsigned int packbf(float lo, float hi) {
    return (unsigned int)f2b(lo) | ((unsigned int)f2b(hi) << 16);
}

// ---------------------------------------------------------------------------
// k_prep: pack all 4 weights into bf16 MFMA-B layout + edge degree count.
// ---------------------------------------------------------------------------
__device__ __forceinline__ void pack_one(const float* __restrict__ W, int K, int N,
                                         int Npad, u16* __restrict__ pb, int idx)
{
    int k = idx / Npad, n = idx - k * Npad;
    float v = (n < N) ? W[(size_t)k * N + n] : 0.f;
    int K5 = K >> 5;
    size_t o = ((size_t)(n >> 4) * K5 + (k >> 5)) * 512
             + ((size_t)((k >> 3) & 3)) * 128 + (n & 15) * 8 + (k & 7);
    pb[o] = f2b(v);
}

__launch_bounds__(256)
__global__ void k_prep(const float* __restrict__ fw_W, const float* __restrict__ c1_W,
                       const float* __restrict__ c2_W, const float* __restrict__ l2_W,
                       u16* __restrict__ pb_l1, u16* __restrict__ pb_c1,
                       u16* __restrict__ pb_c2, u16* __restrict__ pb_f,
                       const int* __restrict__ dst, int E, int* __restrict__ counts)
{
    int idx = blockIdx.x * 256 + threadIdx.x;
    if (idx < 32768) { pack_one(fw_W, 256, 128, 128, pb_l1, idx); return; }
    idx -= 32768;
    if (idx < 65536) { pack_one(c1_W, 128, 512, 512, pb_c1, idx); return; }
    idx -= 65536;
    if (idx < 65536) { pack_one(c2_W, 512, 128, 128, pb_c2, idx); return; }
    idx -= 65536;
    if (idx < 49152) { pack_one(l2_W, 768, 40, 64, pb_f, idx); return; }
    idx -= 49152;
    if (idx < E) atomicAdd(&counts[dst[idx]], 1);
}

// ---------------------------------------------------------------------------
// Fused: layer-1 MFMA GEMM (h1 = lrelu(x@fw_W+b), 2 row-frags/wave, no LDS)
// UNION CSR scatter (block-range split; both outputs consumed by LATER
// dispatches only — no in-kernel cross-block data flow).
// ---------------------------------------------------------------------------
__launch_bounds__(256)
__global__ void k_l1sc(const float* __restrict__ x, const u16* __restrict__ pb,
                       u16* __restrict__ h1, int M, const float* __restrict__ bias,
                       int mb2, const int* __restrict__ ei, int E,
                       const int* __restrict__ rowstart, int* __restrict__ fill,
                       int* __restrict__ csr)
{
    if ((int)blockIdx.x >= mb2) {
        // ---- scatter part (whole block; kernel has no barriers) ----
        int e = ((int)blockIdx.x - mb2) * 256 + threadIdx.x;
        if (e < E) {
            int s = ei[e], d = ei[E + e];
            int pos = rowstart[d] + atomicAdd(&fill[d], 1);
            csr[pos] = s;
        }
        return;
    }
    // ---- GEMM part: 128 rows/block, 128 cols, K=256 ----
    const int tid = threadIdx.x;
    const int w = tid >> 6, l = tid & 63;
    const int lo = l & 15, hi = l >> 4;
    const int row0 = blockIdx.x * 128 + w * 32;
    if (row0 >= M) return;

    f32x4 acc[8][2];
    #pragma unroll
    for (int i = 0; i < 8; ++i)
        #pragma unroll
        for (int s = 0; s < 2; ++s) acc[i][s] = (f32x4){0.f, 0.f, 0.f, 0.f};

    int arow[2];
    #pragma unroll
    for (int s = 0; s < 2; ++s) {
        int r = row0 + s * 16 + lo;
        arow[s] = r < M ? r : M - 1;
    }

    for (int k5 = 0; k5 < 8; ++k5) {
        const int ak = k5 * 32 + hi * 8;
        s16x8 af[2];
        #pragma unroll
        for (int s = 0; s < 2; ++s) {
            const float* A = x + (size_t)arow[s] * 256 + ak;
            float4 v0 = *reinterpret_cast<const float4*>(A);
            float4 v1 = *reinterpret_cast<const float4*>(A + 4);
            U8 au;
            au.q.x = packbf(v0.x, v0.y); au.q.y = packbf(v0.z, v0.w);
            au.q.z = packbf(v1.x, v1.y); au.q.w = packbf(v1.z, v1.w);
            af[s] = au.v;
        }
        #pragma unroll
        for (int cb = 0; cb < 8; ++cb) {
            s16x8 bf = *reinterpret_cast<const s16x8*>(pb + ((size_t)cb * 8 + k5) * 512 + l * 8);
            acc[cb][0] = __builtin_amdgcn_mfma_f32_16x16x32_bf16(af[0], bf, acc[cb][0], 0, 0, 0);
            acc[cb][1] = __builtin_amdgcn_mfma_f32_16x16x32_bf16(af[1], bf, acc[cb][1], 0, 0, 0);
        }
    }

    #pragma unroll
    for (int cb = 0; cb < 8; ++cb) {
        int col = cb * 16 + lo;
        #pragma unroll
        for (int s = 0; s < 2; ++s) {
            #pragma unroll
            for (int p = 0; p < 4; ++p) {
                int r = row0 + s * 16 + hi * 4 + p;
                if (r < M) {
                    float v = acc[cb][s][p] + bias[col];
                    v = v >= 0.f ? v : 0.01f * v;
                    h1[(size_t)r * 128 + col] = f2b(v);
                }
            }
        }
    }
}

// ---------------------------------------------------------------------------
// MFMA GEMM, 2 row-fragments per wave (generic; used for c1/c2 projections).
// HEADS_PB>0: fused GAT alpha epilogue (head width 128 cols; NFRAG=8 -> one
// head per block: h = blockIdx.x).
// ---------------------------------------------------------------------------
template<int NFRAG, bool BN_A, int HEADS_PB>
__launch_bounds__(256)
__global__ void k_mgemm(const u16* __restrict__ Av, int lda, int K,
                        const u16* __restrict__ pb,
                        u16* __restrict__ C, int ldc, int M,
                        const float* __restrict__ scale, const float* __restrict__ shift,
                        const float* __restrict__ aw_s, const float* __restrict__ aw_d,
                        float* __restrict__ as_o, float* __restrict__ ad_o, int nheads)
{
    const int tid = threadIdx.x;
    const int w = tid >> 6, l = tid & 63;
    const int lo = l & 15, hi = l >> 4;
    const int row0 = blockIdx.y * 128 + w * 32;
    if (row0 >= M) return;
    const int cb0 = blockIdx.x * NFRAG;
    const int K5 = K >> 5;

    f32x4 acc[NFRAG][2];
    #pragma unroll
    for (int i = 0; i < NFRAG; ++i)
        #pragma unroll
        for (int s = 0; s < 2; ++s) acc[i][s] = (f32x4){0.f, 0.f, 0.f, 0.f};

    int arow[2];
    #pragma unroll
    for (int s = 0; s < 2; ++s) {
        int r = row0 + s * 16 + lo;
        arow[s] = r < M ? r : M - 1;
    }

    for (int k5 = 0; k5 < K5; ++k5) {
        const int ak = k5 * 32 + hi * 8;
        s16x8 af[2];
        #pragma unroll
        for (int s = 0; s < 2; ++s) {
            uint4 q = *reinterpret_cast<const uint4*>(Av + (size_t)arow[s] * lda + ak);
            float x[8];
            bf2x(q.x, x[0], x[1]); bf2x(q.y, x[2], x[3]);
            bf2x(q.z, x[4], x[5]); bf2x(q.w, x[6], x[7]);
            if (BN_A) {
                #pragma unroll
                for (int j = 0; j < 8; ++j) x[j] = fmaf(x[j], scale[ak + j], shift[ak + j]);
            }
            U8 au;
            au.q.x = packbf(x[0], x[1]); au.q.y = packbf(x[2], x[3]);
            au.q.z = packbf(x[4], x[5]); au.q.w = packbf(x[6], x[7]);
            af[s] = au.v;
        }
        #pragma unroll
        for (int cb = 0; cb < NFRAG; ++cb) {
            s16x8 bf = *reinterpret_cast<const s16x8*>(
                pb + ((size_t)(cb0 + cb) * K5 + k5) * 512 + l * 8);
            acc[cb][0] = __builtin_amdgcn_mfma_f32_16x16x32_bf16(af[0], bf, acc[cb][0], 0, 0, 0);
            acc[cb][1] = __builtin_amdgcn_mfma_f32_16x16x32_bf16(af[1], bf, acc[cb][1], 0, 0, 0);
        }
    }

    #pragma unroll
    for (int cb = 0; cb < NFRAG; ++cb) {
        int col = (cb0 + cb) * 16 + lo;
        #pragma unroll
        for (int s = 0; s < 2; ++s) {
            #pragma unroll
            for (int p = 0; p < 4; ++p) {
                int r = row0 + s * 16 + hi * 4 + p;
                if (r < M) C[(size_t)r * ldc + col] = f2b(acc[cb][s][p]);
            }
        }
    }

    if (HEADS_PB > 0) {
        const int h = (cb0 >> 3);   // NFRAG==8: one head per block
        #pragma unroll
        for (int s = 0; s < 2; ++s) {
            float ps[4] = {0.f,0.f,0.f,0.f}, pd[4] = {0.f,0.f,0.f,0.f};
            #pragma unroll
            for (int cb = 0; cb < NFRAG; ++cb) {
                int col = (cb0 + cb) * 16 + lo;
                float ws = aw_s[col], wd = aw_d[col];
                #pragma unroll
                for (int p = 0; p < 4; ++p) {
                    ps[p] = fmaf(acc[cb][s][p], ws, ps[p]);
                    pd[p] = fmaf(acc[cb][s][p], wd, pd[p]);
                }
            }
            #pragma unroll
            for (int m = 1; m < 16; m <<= 1) {
                #pragma unroll
                for (int p = 0; p < 4; ++p) {
                    ps[p] += __shfl_xor(ps[p], m, 64);
                    pd[p] += __shfl_xor(pd[p], m, 64);
                }
            }
            if (lo == 0) {
                #pragma unroll
                for (int p = 0; p < 4; ++p) {
                    int r = row0 + s * 16 + hi * 4 + p;
                    if (r < M) {
                        as_o[(size_t)r * nheads + h] = ps[p];
                        ad_o[(size_t)r * nheads + h] = pd[p];
                    }
                }
            }
        }
    }
}

// ---------------------------------------------------------------------------
// Final MFMA GEMM (K=768 concat, BN-folded, 2 row-frags/wave) + bias +
// log_softmax. out fp32 [M,40].
// ---------------------------------------------------------------------------
__launch_bounds__(256)
__global__ void k_mfinal(const u16* __restrict__ h1, const u16* __restrict__ h2,
                         const u16* __restrict__ h3,
                         const float* __restrict__ scale, const float* __restrict__ shift,
                         const u16* __restrict__ pb, const float* __restrict__ bias,
                         float* __restrict__ out, int M)
{
    const int tid = threadIdx.x;
    const int w = tid >> 6, l = tid & 63;
    const int lo = l & 15, hi = l >> 4;
    const int row0 = blockIdx.x * 128 + w * 32;
    if (row0 >= M) return;
    const int K5 = 24;   // 768/32

    f32x4 acc[4][2];
    #pragma unroll
    for (int i = 0; i < 4; ++i)
        #pragma unroll
        for (int s = 0; s < 2; ++s) acc[i][s] = (f32x4){0.f, 0.f, 0.f, 0.f};

    int arow[2];
    #pragma unroll
    for (int s = 0; s < 2; ++s) {
        int r = row0 + s * 16 + lo;
        arow[s] = r < M ? r : M - 1;
    }

    for (int k5 = 0; k5 < K5; ++k5) {
        const int kk = k5 * 32 + hi * 8;   // region-uniform per k5
        const u16* src; int ld, offk;
        if (kk < 128)      { src = h1; ld = 128; offk = kk; }
        else if (kk < 640) { src = h2; ld = 512; offk = kk - 128; }
        else               { src = h3; ld = 128; offk = kk - 640; }
        s16x8 af[2];
        #pragma unroll
        for (int s = 0; s < 2; ++s) {
            uint4 q = *reinterpret_cast<const uint4*>(src + (size_t)arow[s] * ld + offk);
            float x[8];
            bf2x(q.x, x[0], x[1]); bf2x(q.y, x[2], x[3]);
            bf2x(q.z, x[4], x[5]); bf2x(q.w, x[6], x[7]);
            #pragma unroll
            for (int j = 0; j < 8; ++j) x[j] = fmaf(x[j], scale[kk + j], shift[kk + j]);
            U8 au;
            au.q.x = packbf(x[0], x[1]); au.q.y = packbf(x[2], x[3]);
            au.q.z = packbf(x[4], x[5]); au.q.w = packbf(x[6], x[7]);
            af[s] = au.v;
        }
        #pragma unroll
        for (int cb = 0; cb < 4; ++cb) {
            s16x8 bf = *reinterpret_cast<const s16x8*>(pb + ((size_t)cb * K5 + k5) * 512 + l * 8);
            acc[cb][0] = __builtin_amdgcn_mfma_f32_16x16x32_bf16(af[0], bf, acc[cb][0], 0, 0, 0);
            acc[cb][1] = __builtin_amdgcn_mfma_f32_16x16x32_bf16(af[1], bf, acc[cb][1], 0, 0, 0);
        }
    }

    #pragma unroll
    for (int s = 0; s < 2; ++s) {
        #pragma unroll
        for (int p = 0; p < 4; ++p) {
            int r = row0 + s * 16 + hi * 4 + p;
            float z0 = acc[0][s][p] + bias[lo];
            float z1 = acc[1][s][p] + bias[16 + lo];
            float z2 = -INF_F;
            if (lo < 8) z2 = acc[2][s][p] + bias[32 + lo];
            float mx = fmaxf(fmaxf(z0, z1), z2);
            #pragma unroll
            for (int m = 1; m < 16; m <<= 1) mx = fmaxf(mx, __shfl_xor(mx, m, 64));
            float se = __expf(z0 - mx) + __expf(z1 - mx) + ((lo < 8) ? __expf(z2 - mx) : 0.f);
            #pragma unroll
            for (int m = 1; m < 16; m <<= 1) se += __shfl_xor(se, m, 64);
            float lse = mx + __logf(se);
            if (r < M) {
                out[(size_t)r * 40 + lo]      = z0 - lse;
                out[(size_t)r * 40 + 16 + lo] = z1 - lse;
                if (lo < 8) out[(size_t)r * 40 + 32 + lo] = z2 - lse;
            }
        }
    }
}

// ---------------------------------------------------------------------------
// BN stats stage 1: per-block column partial sums/sumsq of bf16 matrix.
// ---------------------------------------------------------------------------
__launch_bounds__(256)
__global__ void k_colstats(const u16* __restrict__ X, int M, int C,
                           float* __restrict__ psum, float* __restrict__ psq)
{
    const int CG  = C >> 3;
    const int RPI = 256 / CG;
    const int tid = threadIdx.x;
    const int cg  = tid & (CG - 1);
    const int ro  = tid / CG;
    const int nb  = gridDim.x;
    const int rows_chunk = (M + nb - 1) / nb;
    const int r0 = blockIdx.x * rows_chunk;
    const int r1 = min(M, r0 + rows_chunk);

    float s[8] = {}, q[8] = {};
    for (int r = r0 + ro; r < r1; r += RPI) {
        uint4 u = *reinterpret_cast<const uint4*>(X + (size_t)r * C + cg * 8);
        float x[8];
        bf2x(u.x, x[0], x[1]); bf2x(u.y, x[2], x[3]);
        bf2x(u.z, x[4], x[5]); bf2x(u.w, x[6], x[7]);
        #pragma unroll
        for (int j = 0; j < 8; ++j) { s[j] += x[j]; q[j] = fmaf(x[j], x[j], q[j]); }
    }

    __shared__ float lsum[8][256];
    __shared__ float lsq [8][256];
    #pragma unroll
    for (int j = 0; j < 8; ++j) { lsum[j][tid] = s[j]; lsq[j][tid] = q[j]; }
    __syncthreads();

    if (tid < CG) {
        #pragma unroll
        for (int j = 0; j < 8; ++j) {
            float ss = 0.f, qq = 0.f;
            for (int o = 0; o < RPI; ++o) {
                ss += lsum[j][o * CG + tid];
                qq += lsq [j][o * CG + tid];
            }
            psum[(size_t)blockIdx.x * C + tid * 8 + j] = ss;
            psq [(size_t)blockIdx.x * C + tid * 8 + j] = qq;
        }
    }
}

__launch_bounds__(256)
__global__ void k_colred(const float* __restrict__ psum, const float* __restrict__ psq,
                         const float* __restrict__ g, const float* __restrict__ b,
                         int nb, int M, int C,
                         float* __restrict__ scale, float* __restrict__ shift)
{
    int c = blockIdx.x * 4 + (threadIdx.x >> 6);
    int lane = threadIdx.x & 63;
    if (c >= C) return;
    float s = 0.f, q = 0.f;
    for (int l = lane; l < nb; l += 64) {
        s += psum[(size_t)l * C + c];
        q += psq [(size_t)l * C + c];
    }
    #pragma unroll
    for (int off = 32; off; off >>= 1) {
        s += __shfl_xor(s, off, 64);
        q += __shfl_xor(q, off, 64);
    }
    if (lane == 0) {
        float mu  = s / (float)M;
        float var = q / (float)M - mu * mu;
        float sc  = g[c] * rsqrtf(var + 1e-5f);
        scale[c] = sc;
        shift[c] = b[c] - mu * sc;
    }
}

// ---------------------------------------------------------------------------
// Hierarchical scan: scan1 (per-tile local scan + fill zeroing), scan3 (add
// tile offsets, each block wave-reduces the <=64 tile sums it needs).
// ---------------------------------------------------------------------------
__launch_bounds__(256)
__global__ void k_scan1(const int* __restrict__ counts, int n,
                        int* __restrict__ rowstart, int* __restrict__ tilesum,
                        int* __restrict__ fill)
{
    const int tid = threadIdx.x;
    const int lane = tid & 63, w = tid >> 6;
    const int i0 = blockIdx.x * 1024 + tid * 4;
    int v0 = 0, v1 = 0, v2 = 0, v3 = 0;
    if (i0 + 3 < n) {
        int4 q = *reinterpret_cast<const int4*>(counts + i0);
        v0 = q.x; v1 = q.y; v2 = q.z; v3 = q.w;
    } else if (i0 < n) {
        v0 = counts[i0];
        if (i0 + 1 < n) v1 = counts[i0 + 1];
        if (i0 + 2 < n) v2 = counts[i0 + 2];
    }
    // zero fill[] for the scatter pass (runs in a later dispatch)
    if (i0 < n) {
        int4 z = make_int4(0, 0, 0, 0);
        if (i0 + 3 < n) *reinterpret_cast<int4*>(fill + i0) = z;
        else {
            fill[i0] = 0;
            if (i0 + 1 < n) fill[i0 + 1] = 0;
            if (i0 + 2 < n) fill[i0 + 2] = 0;
        }
    }
    int s1 = v0 + v1, s2 = s1 + v2, s3 = s2 + v3;
    int x = s3;
    #pragma unroll
    for (int off = 1; off < 64; off <<= 1) {
        int t = __shfl_up(x, off, 64);
        if (lane >= off) x += t;
    }
    __shared__ int wsum[4];
    if (lane == 63) wsum[w] = x;
    __syncthreads();
    int woff = 0;
    #pragma unroll
    for (int i = 0; i < 4; ++i)
        if (i < w) woff += wsum[i];
    int excl = woff + x - s3;
    if (i0 + 0 < n) rowstart[i0 + 1] = excl + v0;
    if (i0 + 1 < n) rowstart[i0 + 2] = excl + s1;
    if (i0 + 2 < n) rowstart[i0 + 3] = excl + s2;
    if (i0 + 3 < n) rowstart[i0 + 4] = excl + s3;
    if (tid == 255) tilesum[blockIdx.x] = wsum[0] + wsum[1] + wsum[2] + wsum[3];
}

__launch_bounds__(256)
__global__ void k_scan3(int* __restrict__ rowstart, const int* __restrict__ tilesum, int n)
{
    const int tile = (int)((blockIdx.x * 256) >> 10);
    __shared__ int s_off;
    if (threadIdx.x < 64) {
        int lane = threadIdx.x;
        int v = (lane < tile) ? tilesum[lane] : 0;   // tile count <= 49 < 64
        #pragma unroll
        for (int m = 1; m < 64; m <<= 1) v += __shfl_xor(v, m, 64);
        if (lane == 0) s_off = v;
    }
    __syncthreads();
    int i = blockIdx.x * 256 + threadIdx.x;
    if (i < n) rowstart[i + 1] += s_off;
    if (blockIdx.x == 0 && threadIdx.x == 0) rowstart[0] = 0;
}

// ---------------------------------------------------------------------------
// GAT aggregation, HEADS=4: one wave per dst, two-pass softmax,
// depth-8 prefetch / unroll-4. lane l: head=l>>4, dims (l&15)*8..+8.
// ---------------------------------------------------------------------------
__launch_bounds__(256)
__global__ void k_gat_agg_h4(const u16* __restrict__ hp,
                             const float* __restrict__ as_, const float* __restrict__ ad_,
                             const int* __restrict__ rowstart, const int* __restrict__ csr,
                             const float* __restrict__ bias, u16* __restrict__ out, int Nn)
{
    int d = (int)((blockIdx.x * (size_t)blockDim.x + threadIdx.x) >> 6);
    int lane = threadIdx.x & 63;
    if (d >= Nn) return;
    const int h = lane >> 4;
    const int li = lane & 15;
    const int dim = li * 8;
    int e0 = rowstart[d], e1 = rowstart[d + 1];
    float adv = ad_[(size_t)d * 4 + h];

    // ---- pass 1: per-head max ----
    float mx = -INF_F;
    for (int j = e0 + li; j < e1; j += 16) {
        int s = csr[j];
        float e = as_[(size_t)s * 4 + h] + adv;
        e = e >= 0.f ? e : 0.2f * e;
        mx = fmaxf(mx, e);
    }
    #pragma unroll
    for (int m = 1; m < 16; m <<= 1) mx = fmaxf(mx, __shfl_xor(mx, m, 64));

    // ---- pass 2: depth-8 prefetch, unroll-4, no rescale ----
    float lsum = 0.f;
    float acc[8] = {};

    #define F4(J, A, U) { int jj = min((J), e1 - 1); int s_ = csr[jj];                \
        A = as_[(size_t)s_ * 4 + h];                                                  \
        U = *reinterpret_cast<const uint4*>(hp + ((size_t)s_ * 4 + h) * 128 + dim); }
    #define C4(A, U) { float e_ = A + adv; e_ = e_ >= 0.f ? e_ : 0.2f * e_;           \
        float w_ = __expf(e_ - mx); lsum += w_;                                       \
        float x_[8];                                                                  \
        bf2x(U.x, x_[0], x_[1]); bf2x(U.y, x_[2], x_[3]);                             \
        bf2x(U.z, x_[4], x_[5]); bf2x(U.w, x_[6], x_[7]);                             \
        _Pragma("unroll")                                                             \
        for (int t_ = 0; t_ < 8; ++t_) acc[t_] = fmaf(x_[t_], w_, acc[t_]); }

    float a0, a1, a2, a3, a4, a5, a6, a7;
    uint4 u0, u1, u2, u3, u4, u5, u6, u7;
    F4(e0 + 0, a0, u0); F4(e0 + 1, a1, u1); F4(e0 + 2, a2, u2); F4(e0 + 3, a3, u3);
    F4(e0 + 4, a4, u4); F4(e0 + 5, a5, u5); F4(e0 + 6, a6, u6); F4(e0 + 7, a7, u7);

    int j = e0;
    for (; j + 3 < e1; j += 4) {
        C4(a0, u0); C4(a1, u1); C4(a2, u2); C4(a3, u3);
        a0 = a4; u0 = u4; a1 = a5; u1 = u5; a2 = a6; u2 = u6; a3 = a7; u3 = u7;
        F4(j + 8, a4, u4); F4(j + 9, a5, u5); F4(j + 10, a6, u6); F4(j + 11, a7, u7);
    }
    if (j < e1)     C4(a0, u0);
    if (j + 1 < e1) C4(a1, u1);
    if (j + 2 < e1) C4(a2, u2);
    #undef F4
    #undef C4

    float inv = 1.f / (lsum + 1e-16f);
    const int ob = h * 128 + dim;
    float v[8];
    #pragma unroll
    for (int t = 0; t < 8; ++t) {
        float z = acc[t] * inv + bias[ob + t];
        v[t] = z >= 0.f ? z : 0.01f * z;
    }
    uint4 o;
    o.x = packbf(v[0], v[1]); o.y = packbf(v[2], v[3]);
    o.z = packbf(v[4], v[5]); o.w = packbf(v[6], v[7]);
    *reinterpret_cast<uint4*>(out + (size_t)d * 512 + ob) = o;
}

// ---------------------------------------------------------------------------
// GAT aggregation, HEADS=1: TWO dsts per wave, split-half (lanes 0-31 = dst A,
// lanes 32-63 = dst B; 4 dims/lane -> 8B loads). Two-pass softmax; depth-8
// prefetch / unroll-4; exhausted half predicated via w=0.
// ---------------------------------------------------------------------------
__launch_bounds__(256)
__global__ void k_gat_agg_h1(const u16* __restrict__ hp,
                             const float* __restrict__ as_, const float* __restrict__ ad_,
                             const int* __restrict__ rowstart, const int* __restrict__ csr,
                             const float* __restrict__ bias, u16* __restrict__ out, int Nn)
{
    const int lane = threadIdx.x & 63;
    const int half = lane >> 5;          // 0 or 1
    const int sl = lane & 31;
    const int wave = (int)((blockIdx.x * (size_t)blockDim.x + threadIdx.x) >> 6);
    const int d = wave * 2 + half;
    if (wave * 2 >= Nn) return;
    const bool act = d < Nn;
    const int dc = act ? d : (Nn - 1);
    const int dim = sl * 4;              // 4 dims per lane
    int e0 = rowstart[dc], e1 = rowstart[dc + 1];
    int len = e1 - e0;
    float adv = ad_[dc];

    // ---- pass 1: max over this half's edges (32 lanes stride) ----
    float mx = -INF_F;
    for (int j = e0 + sl; j < e1; j += 32) {
        int s = csr[j];
        float e = as_[s] + adv;
        e = e >= 0.f ? e : 0.2f * e;
        mx = fmaxf(mx, e);
    }
    #pragma unroll
    for (int m = 1; m < 32; m <<= 1) mx = fmaxf(mx, __shfl_xor(mx, m, 32));

    // wave-uniform trip count
    int maxlen = max(len, __shfl_xor(len, 32, 64));

    // ---- pass 2: depth-8 prefetch, unroll-4; per-half predication ----
    float lsum = 0.f;
    float acc[4] = {};

    #define F1(JR, A, U) { int jj = e0 + min((JR), len - 1); int s_ = csr[jj];        \
        A = as_[s_];                                                                  \
        U = *reinterpret_cast<const uint2*>(hp + (size_t)s_ * 128 + dim); }
    #define C1(JR, A, U) { float e_ = A + adv; e_ = e_ >= 0.f ? e_ : 0.2f * e_;       \
        float w_ = ((JR) < len) ? __expf(e_ - mx) : 0.f;                              \
        float x0_, x1_, x2_, x3_; bf2x(U.x, x0_, x1_); bf2x(U.y, x2_, x3_);           \
        lsum += w_;                                                                   \
        acc[0] = fmaf(x0_, w_, acc[0]); acc[1] = fmaf(x1_, w_, acc[1]);               \
        acc[2] = fmaf(x2_, w_, acc[2]); acc[3] = fmaf(x3_, w_, acc[3]); }

    float a0, a1, a2, a3, a4, a5, a6, a7;
    uint2 u0, u1, u2, u3, u4, u5, u6, u7;
    F1(0, a0, u0); F1(1, a1, u1); F1(2, a2, u2); F1(3, a3, u3);
    F1(4, a4, u4); F1(5, a5, u5); F1(6, a6, u6); F1(7, a7, u7);

    int jr = 0;
    for (; jr + 3 < maxlen; jr += 4) {
        C1(jr + 0, a0, u0); C1(jr + 1, a1, u1); C1(jr + 2, a2, u2); C1(jr + 3, a3, u3);
        a0 = a4; u0 = u4; a1 = a5; u1 = u5; a2 = a6; u2 = u6; a3 = a7; u3 = u7;
        F1(jr + 8, a4, u4); F1(jr + 9, a5, u5); F1(jr + 10, a6, u6); F1(jr + 11, a7, u7);
    }
    if (jr < maxlen)     C1(jr + 0, a0, u0);
    if (jr + 1 < maxlen) C1(jr + 1, a1, u1);
    if (jr + 2 < maxlen) C1(jr + 2, a2, u2);
    #undef F1
    #undef C1

    float inv = 1.f / (lsum + 1e-16f);
    float v0 = acc[0] * inv + bias[dim];
    float v1 = acc[1] * inv + bias[dim + 1];
    float v2 = acc[2] * inv + bias[dim + 2];
    float v3 = acc[3] * inv + bias[dim + 3];
    v0 = v0 >= 0.f ? v0 : 0.01f * v0;
    v1 = v1 >= 0.f ? v1 : 0.01f * v1;
    v2 = v2 >= 0.f ? v2 : 0.01f * v2;
    v3 = v3 >= 0.f ? v3 : 0.01f * v3;
    if (act) {
        uint2 o;
        o.x = packbf(v0, v1);
        o.y = packbf(v2, v3);
        *reinterpret_cast<uint2*>(out + (size_t)d * 128 + dim) = o;
    }
}

// ---------------------------------------------------------------------------
extern "C" void kernel_launch(void* const* d_in, const int* in_sizes, int n_in,
                              void* d_out, int out_size, void* d_ws, size_t ws_size,
                              hipStream_t stream)
{
    const float* x     = (const float*)d_in[0];
    const int*   ei    = (const int*)  d_in[1];
    const float* fw_W  = (const float*)d_in[2];
    const float* fw_b  = (const float*)d_in[3];
    const float* c1_W  = (const float*)d_in[4];
    const float* c1_as = (const float*)d_in[5];
    const float* c1_ad = (const float*)d_in[6];
    const float* c1_b  = (const float*)d_in[7];
    const float* c2_W  = (const float*)d_in[8];
    const float* c2_as = (const float*)d_in[9];
    const float* c2_ad = (const float*)d_in[10];
    const float* c2_b  = (const float*)d_in[11];
    const float* bn1_g = (const float*)d_in[12];
    const float* bn1_b = (const float*)d_in[13];
    const float* bn2_g = (const float*)d_in[14];
    const float* bn2_b = (const float*)d_in[15];
    const float* bn3_g = (const float*)d_in[16];
    const float* bn3_b = (const float*)d_in[17];
    const float* l2_W  = (const float*)d_in[18];
    const float* l2_b  = (const float*)d_in[19];
    float* out = (float*)d_out;

    const int N = in_sizes[0] / 256;   // 50000
    const int E = in_sizes[1] / 2;     // 850000
    const int NB = 256;

    char* base = (char*)d_ws;
    size_t off = 0;
    auto alloc = [&](size_t bytes) -> void* {
        void* p = (void*)(base + off);
        off = (off + bytes + 255) & ~(size_t)255;
        return p;
    };
    // --- zeroed region (counts only; fill zeroed by scan1) ---
    int*   counts = (int*)  alloc((size_t)N * 4);
    size_t zero_bytes = off;
    // --- rest ---
    const int SCB = (N + 1023) / 1024;
    int*   fill     = (int*)  alloc((size_t)N * 4);
    float* as1      = (float*)alloc((size_t)N * 4 * 4);
    float* ad1      = (float*)alloc((size_t)N * 4 * 4);
    float* as2      = (float*)alloc((size_t)N * 4);
    float* ad2      = (float*)alloc((size_t)N * 4);
    float* psum     = (float*)alloc((size_t)NB * 512 * 4);
    float* psq      = (float*)alloc((size_t)NB * 512 * 4);
    int*   rowstart = (int*)  alloc((size_t)(N + 1) * 4);
    int*   tilesum  = (int*)  alloc((size_t)SCB * 4);
    int*   csr      = (int*)  alloc((size_t)E * 4);
    float* scale768 = (float*)alloc(768 * 4);
    float* shift768 = (float*)alloc(768 * 4);
    u16*   pb_l1    = (u16*)  alloc((size_t)256 * 128 * 2);
    u16*   pb_c1    = (u16*)  alloc((size_t)128 * 512 * 2);
    u16*   pb_c2    = (u16*)  alloc((size_t)512 * 128 * 2);
    u16*   pb_f     = (u16*)  alloc((size_t)768 * 64 * 2);
    u16*   h1       = (u16*)  alloc((size_t)N * 128 * 2);
    u16*   h2       = (u16*)  alloc((size_t)N * 512 * 2);
    u16*   hp1      = (u16*)  alloc((size_t)N * 512 * 2);  // dead after agg1:
    u16*   hp2      = hp1;                                  //  reuse for hp2 [N,128]
    u16*   h3       = hp1 + (size_t)N * 128;                //  and h3 [N,128]
    (void)ws_size; (void)n_in; (void)out_size;

    const int mb2 = (N + 127) / 128;                 // 391 (128 rows/block)
    const int scb = (E + 255) / 256;                 // scatter blocks
    const int wave_blocks = (int)(((size_t)N * 64 + 255) / 256);
    const int h1_wave_blocks = (int)((((size_t)N + 1) / 2 * 64 + 255) / 256);
    const int PK = 32768 + 65536 + 65536 + 49152;

    hipMemsetAsync(base, 0, zero_bytes, stream);

    // pack all weights + edge count (one launch)
    k_prep<<<(PK + E + 255) / 256, 256, 0, stream>>>(
        fw_W, c1_W, c2_W, l2_W, pb_l1, pb_c1, pb_c2, pb_f, ei + E, E, counts);

    // hierarchical scan: counts -> rowstart (+ fill zeroing)
    k_scan1<<<SCB, 256, 0, stream>>>(counts, N, rowstart, tilesum, fill);
    k_scan3<<<(N + 255) / 256, 256, 0, stream>>>(rowstart, tilesum, N);

    // layer-1 GEMM fused with CSR scatter (independent work, one launch)
    k_l1sc<<<mb2 + scb, 256, 0, stream>>>(
        x, pb_l1, h1, N, fw_b, mb2, ei, E, rowstart, fill, csr);

    // BN1
    k_colstats<<<NB, 256, 0, stream>>>(h1, N, 128, psum, psq);
    k_colred<<<(128 + 3) / 4, 256, 0, stream>>>(psum, psq, bn1_g, bn1_b, NB, N, 128,
                                                scale768, shift768);

    // conv1 projection + fused alpha (1 head per 128-col block, grid.x = 4)
    k_mgemm<8, true, 1><<<dim3(4, mb2), 256, 0, stream>>>(
        h1, 128, 128, pb_c1, hp1, 512, N, scale768, shift768,
        c1_as, c1_ad, as1, ad1, 4);
    k_gat_agg_h4<<<wave_blocks, 256, 0, stream>>>(
        hp1, as1, ad1, rowstart, csr, c1_b, h2, N);

    // BN2
    k_colstats<<<NB, 256, 0, stream>>>(h2, N, 512, psum, psq);
    k_colred<<<(512 + 3) / 4, 256, 0, stream>>>(psum, psq, bn2_g, bn2_b, NB, N, 512,
                                                scale768 + 128, shift768 + 128);

    // conv2 projection + fused alpha
    k_mgemm<8, true, 1><<<dim3(1, mb2), 256, 0, stream>>>(
        h2, 512, 512, pb_c2, hp2, 128, N, scale768 + 128, shift768 + 128,
        c2_as, c2_ad, as2, ad2, 1);
    k_gat_agg_h1<<<h1_wave_blocks, 256, 0, stream>>>(
        hp2, as2, ad2, rowstart, csr, c2_b, h3, N);

    // BN3
    k_colstats<<<NB, 256, 0, stream>>>(h3, N, 128, psum, psq);
    k_colred<<<(128 + 3) / 4, 256, 0, stream>>>(psum, psq, bn3_g, bn3_b, NB, N, 128,
                                                scale768 + 640, shift768 + 640);

    // final fused GEMM + log_softmax
    k_mfinal<<<mb2, 256, 0, stream>>>(h1, h2, h3, scale768, shift768, pb_f, l2_b, out, N);
}